// Round 7
// baseline (4380.383 us; speedup 1.0000x reference)
//
#include <hip/hip_runtime.h>
#include <hip/hip_fp16.h>

// LSTM: B=32, T=512, D=1024, H=1024.
// wtrans ; xcvt ; proj (fp16 MFMA) ; persistent recurrent kernel with
// TAG-EMBEDDED h exchange: h published as u32 = (tag<<16)|fp16, sc0/sc1 stores
// with NO drain; readers load+retry until tags match. No flags, no poll phase,
// one __syncthreads per step. h buffers memset each launch (kills stale tags
// across graph replays).

typedef __attribute__((ext_vector_type(8))) _Float16 f16x8;
typedef __attribute__((ext_vector_type(4))) float    f32x4;

__device__ __forceinline__ float sigm_f(float x) { return 1.0f / (1.0f + __expf(-x)); }
__device__ __forceinline__ float tanh_f(float x) { return 1.0f - 2.0f / (__expf(2.0f * x) + 1.0f); }

__device__ __forceinline__ void ld_sys_u128(uint4& d, const void* p) {
    asm volatile("global_load_dwordx4 %0, %1, off sc0 sc1" : "=v"(d) : "v"(p) : "memory");
}
__device__ __forceinline__ void st_sys_u32(void* p, unsigned v) {
    asm volatile("global_store_dword %0, %1, off sc0 sc1" :: "v"(p), "v"(v) : "memory");
}

// pack low halves of 8 tagged u32s (k-ascending) into one f16x8 A-fragment
__device__ __forceinline__ f16x8 pack_h(const uint4& u, const uint4& v) {
    union { unsigned w[4]; f16x8 h; } r;
    r.w[0] = (u.y << 16) | (u.x & 0xFFFFu);
    r.w[1] = (u.w << 16) | (u.z & 0xFFFFu);
    r.w[2] = (v.y << 16) | (v.x & 0xFFFFu);
    r.w[3] = (v.w << 16) | (v.z & 0xFFFFu);
    return r.h;
}

// ---------------- X -> fp16 ----------------
__global__ __launch_bounds__(256)
void xcvt_kernel(const float* __restrict__ X, unsigned short* __restrict__ Xh)
{
    int i = blockIdx.x * 256 + threadIdx.x;
    float4 v0 = *reinterpret_cast<const float4*>(X + (size_t)i * 8);
    float4 v1 = *reinterpret_cast<const float4*>(X + (size_t)i * 8 + 4);
    unsigned short o[8];
    o[0] = __half_as_ushort(__float2half_rn(v0.x));
    o[1] = __half_as_ushort(__float2half_rn(v0.y));
    o[2] = __half_as_ushort(__float2half_rn(v0.z));
    o[3] = __half_as_ushort(__float2half_rn(v0.w));
    o[4] = __half_as_ushort(__float2half_rn(v1.x));
    o[5] = __half_as_ushort(__float2half_rn(v1.y));
    o[6] = __half_as_ushort(__float2half_rn(v1.z));
    o[7] = __half_as_ushort(__float2half_rn(v1.w));
    *reinterpret_cast<int4*>(Xh + (size_t)i * 8) = *reinterpret_cast<int4*>(o);
}

// ---------------- W transpose + fp16 convert ----------------
__global__ __launch_bounds__(256)
void wtrans_kernel(const float* __restrict__ Wa, const float* __restrict__ Wi,
                   const float* __restrict__ Wf, const float* __restrict__ Wo,
                   unsigned short* __restrict__ Wt)
{
    __shared__ float Ts[64][65];
    const int bx = blockIdx.x;
    const int g  = bx >> 8;
    const int k0 = ((bx >> 4) & 15) * 64;
    const int c0 = (bx & 15) * 64;
    const float* W = (g == 0) ? Wa : ((g == 1) ? Wi : ((g == 2) ? Wf : Wo));
    const int tid = threadIdx.x;
#pragma unroll
    for (int u = 0; u < 4; ++u) {
        int r  = u * 16 + (tid >> 4);
        int c4 = (tid & 15) * 4;
        float4 v = *reinterpret_cast<const float4*>(W + (size_t)(k0 + r) * 1024 + c0 + c4);
        Ts[r][c4 + 0] = v.x; Ts[r][c4 + 1] = v.y; Ts[r][c4 + 2] = v.z; Ts[r][c4 + 3] = v.w;
    }
    __syncthreads();
#pragma unroll
    for (int u = 0; u < 4; ++u) {
        int col = u * 16 + (tid >> 4);
        int k4  = (tid & 15) * 4;
        unsigned short o[4];
#pragma unroll
        for (int j = 0; j < 4; ++j)
            o[j] = __half_as_ushort(__float2half_rn(Ts[k4 + j][col]));
        *reinterpret_cast<ushort4*>(Wt + ((size_t)g * 1024 + c0 + col) * 1024 + k0 + k4) =
            *reinterpret_cast<ushort4*>(o);
    }
}

// ---------------- Projection GEMM via fp16 MFMA ----------------
__global__ __launch_bounds__(256)
void proj_mfma(const _Float16* __restrict__ Xh,
               const _Float16* __restrict__ Wt,
               unsigned short* __restrict__ xg)
{
    __shared__ _Float16 As[128 * 40];
    __shared__ _Float16 Bs[128 * 40];

    const int tid  = threadIdx.x;
    const int bn   = blockIdx.x & 31;
    const int bm   = blockIdx.x >> 5;
    const int row0 = bm * 128, col0 = bn * 128;
    const int w    = tid >> 6, lane = tid & 63;
    const int wm   = w >> 1,  wn   = w & 1;
    const int lr   = lane & 15, ko = lane >> 4;

    f32x4 acc[4][4];
#pragma unroll
    for (int mi = 0; mi < 4; ++mi)
#pragma unroll
        for (int ni = 0; ni < 4; ++ni)
            acc[mi][ni] = f32x4{0.f, 0.f, 0.f, 0.f};

    for (int kt = 0; kt < 1024; kt += 32) {
#pragma unroll
        for (int u = 0; u < 2; ++u) {
            int i8  = u * 256 + tid;
            int r   = i8 >> 2, k8 = (i8 & 3) * 8;
            *reinterpret_cast<float4*>(&As[r * 40 + k8]) =
                *reinterpret_cast<const float4*>(Xh + (size_t)(row0 + r) * 1024 + kt + k8);
        }
#pragma unroll
        for (int u = 0; u < 2; ++u) {
            int i8  = u * 256 + tid;
            int col = i8 >> 2, k8 = (i8 & 3) * 8;
            *reinterpret_cast<float4*>(&Bs[col * 40 + k8]) =
                *reinterpret_cast<const float4*>(Wt + (size_t)(col0 + col) * 1024 + kt + k8);
        }
        __syncthreads();

        f16x8 af[4], bf[4];
#pragma unroll
        for (int mi = 0; mi < 4; ++mi)
            af[mi] = *reinterpret_cast<const f16x8*>(&As[(wm * 64 + mi * 16 + lr) * 40 + ko * 8]);
#pragma unroll
        for (int ni = 0; ni < 4; ++ni)
            bf[ni] = *reinterpret_cast<const f16x8*>(&Bs[(wn * 64 + ni * 16 + lr) * 40 + ko * 8]);
#pragma unroll
        for (int mi = 0; mi < 4; ++mi)
#pragma unroll
            for (int ni = 0; ni < 4; ++ni)
                acc[mi][ni] = __builtin_amdgcn_mfma_f32_16x16x32_f16(af[mi], bf[ni], acc[mi][ni], 0, 0, 0);
        __syncthreads();
    }

#pragma unroll
    for (int mi = 0; mi < 4; ++mi)
#pragma unroll
        for (int ni = 0; ni < 4; ++ni)
#pragma unroll
            for (int j = 0; j < 4; ++j) {
                int rt = row0 + wm * 64 + mi * 16 + ko * 4 + j;
                int ct = col0 + wn * 64 + ni * 16 + lr;
                int b = rt >> 9, t = rt & 511;
                xg[((size_t)t * 32 + b) * 4096 + ct] =
                    __half_as_ushort(__float2half_rn(acc[mi][ni][j]));
            }
}

// ---------------- Persistent MFMA recurrent kernel: tag-embedded h ----------------
// 256 blocks x 512 thr. Block blk owns h-cols [blk*4, blk*4+4) -> 16 gate-cols.
// h buffer (per parity): u32[oct 128][row 32][8], u32 = (tag<<16)|fp16.
// Reader at step t requires tag==t on every loaded u32 (retry loop). Writer at
// step t stores tag t+1 into buffer[(t+1)&1] with NO drain. Tag check subsumes
// the grid barrier: reader t+2 passing implies every block finished step t+1,
// so parity-buffer reuse is race-free. Buffers zeroed per launch (stale tags).
__global__ __launch_bounds__(512)
void lstm_persist(const unsigned short* __restrict__ xg,   // [512][32][4096] fp16
                  const float* __restrict__ Wah, const float* __restrict__ Wih,
                  const float* __restrict__ Wfh, const float* __restrict__ Woh,
                  const float* __restrict__ ba, const float* __restrict__ bi,
                  const float* __restrict__ bfv, const float* __restrict__ bo,
                  unsigned short* __restrict__ wpk,        // [256][16384] fp16 B-frag order
                  unsigned* __restrict__ h32A,             // [128][32][8] tagged
                  unsigned* __restrict__ h32B,
                  float* __restrict__ out)                 // [32][512][1024]
{
    __shared__ float pbuf[2][16 * 64 * 4];                 // ping-pong partials (2x16KB)

    const int tid  = threadIdx.x;
    const int blk  = blockIdx.x;
    const int hc0  = blk * 4;
    const int wv   = tid >> 6;
    const int lane = tid & 63;

    // ---- pack Wh slice into B-frag order (once) ----
    unsigned short* wb = wpk + (size_t)blk * 16384;
#pragma unroll
    for (int q = 0; q < 4; ++q) {
        int fq    = tid * 4 + q;
        int kiter = fq >> 6;
        int ln    = fq & 63;
        int col   = ln & 15;
        int g     = col >> 2, c = col & 3;
        int kbase = kiter * 32 + (ln >> 4) * 8;
        const float* Wg = (g == 0) ? Wah : ((g == 1) ? Wih : ((g == 2) ? Wfh : Woh));
        unsigned short tmp[8];
#pragma unroll
        for (int e = 0; e < 8; ++e)
            tmp[e] = __half_as_ushort(__float2half_rn(Wg[(size_t)(kbase + e) * 1024 + hc0 + c]));
        *reinterpret_cast<int4*>(wb + (size_t)fq * 8) = *reinterpret_cast<int4*>(tmp);
    }

    const int row = tid >> 2;          // gate-thread mapping (tid < 128)
    const int hc  = tid & 3;
    float bias_a = 0.f, bias_i = 0.f, bias_f = 0.f, bias_o = 0.f;
    unsigned short xv[4] = {0, 0, 0, 0};   // xg values for the CURRENT step (regs)
    if (tid < 128) {
        bias_a = ba [hc0 + hc];
        bias_i = bi [hc0 + hc];
        bias_f = bfv[hc0 + hc];
        bias_o = bo [hc0 + hc];
#pragma unroll
        for (int g = 0; g < 4; ++g)
            xv[g] = xg[(size_t)row * 4096 + g * 1024 + hc0 + hc];   // t=0
    }
    float sreg = 0.f;

    __syncthreads();                   // wpk visible block-wide

    const int koct = lane >> 4;
    const int arow = lane & 15;

    for (int t = 0; t < 512; ++t) {
        const unsigned* hp = (t & 1) ? h32A : h32B;     // written at t-1, tag t
        unsigned*       hn = (t & 1) ? h32B : h32A;     // we write tag t+1

        if (t > 0) {
            // W frags (L1-hot), independent of h
            f16x8 bfr[4];
#pragma unroll
            for (int ki = 0; ki < 4; ++ki)
                bfr[ki] = *reinterpret_cast<const f16x8*>(wb + ((size_t)((wv * 4 + ki) * 64 + lane) * 8));

            // ---- tagged A-load retry loop ----
            uint4 c0[4][2], c1[4][2];
            const unsigned tt = (unsigned)t;
            for (;;) {
#pragma unroll
                for (int ki = 0; ki < 4; ++ki) {
                    int oct = (wv * 4 + ki) * 4 + koct;
                    const unsigned* p0 = hp + ((size_t)(oct * 32 + arow) * 8);
                    const unsigned* p1 = p0 + 16 * 8;
                    ld_sys_u128(c0[ki][0], p0);
                    ld_sys_u128(c0[ki][1], p0 + 4);
                    ld_sys_u128(c1[ki][0], p1);
                    ld_sys_u128(c1[ki][1], p1 + 4);
                }
                asm volatile("s_waitcnt vmcnt(0)" ::: "memory");
                __builtin_amdgcn_sched_barrier(0);
                unsigned bad = 0;
#pragma unroll
                for (int ki = 0; ki < 4; ++ki)
#pragma unroll
                    for (int h = 0; h < 2; ++h) {
                        bad |= (c0[ki][h].x >> 16) ^ tt;
                        bad |= (c0[ki][h].y >> 16) ^ tt;
                        bad |= (c0[ki][h].z >> 16) ^ tt;
                        bad |= (c0[ki][h].w >> 16) ^ tt;
                        bad |= (c1[ki][h].x >> 16) ^ tt;
                        bad |= (c1[ki][h].y >> 16) ^ tt;
                        bad |= (c1[ki][h].z >> 16) ^ tt;
                        bad |= (c1[ki][h].w >> 16) ^ tt;
                    }
                if (__all(bad == 0)) break;
                __builtin_amdgcn_s_sleep(1);
            }

            f32x4 acc0 = {0.f, 0.f, 0.f, 0.f};
            f32x4 acc1 = {0.f, 0.f, 0.f, 0.f};
#pragma unroll
            for (int ki = 0; ki < 4; ++ki) {
                acc0 = __builtin_amdgcn_mfma_f32_16x16x32_f16(
                    pack_h(c0[ki][0], c0[ki][1]), bfr[ki], acc0, 0, 0, 0);
                acc1 = __builtin_amdgcn_mfma_f32_16x16x32_f16(
                    pack_h(c1[ki][0], c1[ki][1]), bfr[ki], acc1, 0, 0, 0);
            }
            *reinterpret_cast<f32x4*>(&pbuf[t & 1][((wv * 2 + 0) * 64 + lane) * 4]) = acc0;
            *reinterpret_cast<f32x4*>(&pbuf[t & 1][((wv * 2 + 1) * 64 + lane) * 4]) = acc1;
        }
        __syncthreads();               // partials visible (only barrier per step)

        if (tid < 128) {
            // fused 8-way reduce + gates (mapping validated round 6)
            const int m  = row >> 4;
            const int rp = row & 15;
            const int rg = rp & 3;
            const int lh = (rp >> 2) * 16;
            float gsum[4] = {0.f, 0.f, 0.f, 0.f};
            if (t > 0) {
                const float* pb = pbuf[t & 1];
#pragma unroll
                for (int g = 0; g < 4; ++g) {
                    int ln = lh + g * 4 + hc;
                    float s = 0.f;
#pragma unroll
                    for (int w = 0; w < 8; ++w)
                        s += pb[((w * 2 + m) * 64 + ln) * 4 + rg];
                    gsum[g] = s;
                }
            }
            float ga = gsum[0] + bias_a + __half2float(__ushort_as_half(xv[0]));
            float gi = gsum[1] + bias_i + __half2float(__ushort_as_half(xv[1]));
            float gf = gsum[2] + bias_f + __half2float(__ushort_as_half(xv[2]));
            float gO = gsum[3] + bias_o + __half2float(__ushort_as_half(xv[3]));
            float a  = tanh_f(ga);
            float ii = sigm_f(gi);
            float ff = sigm_f(gf);
            float oo = sigm_f(gO);
            sreg = a * ii + sreg * ff;
            float hv = tanh_f(sreg) * oo;

            int colg = hc0 + hc;
            // publish h FIRST (critical path), tag t+1, no drain
            unsigned short h16 = __half_as_ushort(__float2half_rn(hv));
            st_sys_u32(hn + ((size_t)(colg >> 3) * 32 + row) * 8 + (colg & 7),
                       ((unsigned)(t + 1) << 16) | (unsigned)h16);
            out[((size_t)row * 512 + t) * 1024 + colg] = hv;
            // xg for t+1 into regs (latency hidden by next step's retry/MFMA)
            if (t + 1 < 512) {
#pragma unroll
                for (int g = 0; g < 4; ++g)
                    xv[g] = xg[((size_t)(t + 1) * 32 + row) * 4096 + g * 1024 + hc0 + hc];
            }
        }
    }
}

// ---------------- Fallback per-step kernel (fp32) ----------------
template<bool FIRST>
__global__ __launch_bounds__(256)
void step_kernel(const float* __restrict__ hprev, float* __restrict__ hnext,
                 float* __restrict__ sbuf, const float* __restrict__ X,
                 const float* __restrict__ Wah, const float* __restrict__ Wih,
                 const float* __restrict__ Wfh, const float* __restrict__ Woh,
                 const float* __restrict__ Wax, const float* __restrict__ Wix,
                 const float* __restrict__ Wfx, const float* __restrict__ Wox,
                 const float* __restrict__ ba, const float* __restrict__ bi,
                 const float* __restrict__ bfv, const float* __restrict__ bo,
                 float* __restrict__ out, int t)
{
    __shared__ float hs[32 * 1028];
    __shared__ float gs[2][32][16];

    const int tid  = threadIdx.x;
    const int hc0  = blockIdx.x * 4;
    const int kh   = tid >> 7;
    const int gtid = tid & 127;
    const int r    = gtid >> 2;
    const int gate = gtid & 3;
    const int k0   = kh * 512;

    float4 acc = make_float4(0.f, 0.f, 0.f, 0.f);

    if (!FIRST) {
        for (int u = 0; u < 32; u++) {
            int f4 = u * 256 + tid;
            int rr = f4 >> 8;
            int kq = (f4 & 255) << 2;
            *reinterpret_cast<float4*>(&hs[rr * 1028 + kq]) =
                *reinterpret_cast<const float4*>(hprev + rr * 1024 + kq);
        }
        __syncthreads();
        const float* Wg = (gate == 0) ? Wah : ((gate == 1) ? Wih : ((gate == 2) ? Wfh : Woh));
        const float* Wp = Wg + hc0;
#pragma unroll 4
        for (int k = k0; k < k0 + 512; k += 4) {
            float4 hv = *reinterpret_cast<const float4*>(&hs[r * 1028 + k]);
            float4 w0 = *reinterpret_cast<const float4*>(Wp + (size_t)(k + 0) * 1024);
            float4 w1 = *reinterpret_cast<const float4*>(Wp + (size_t)(k + 1) * 1024);
            float4 w2 = *reinterpret_cast<const float4*>(Wp + (size_t)(k + 2) * 1024);
            float4 w3 = *reinterpret_cast<const float4*>(Wp + (size_t)(k + 3) * 1024);
            acc.x += hv.x * w0.x + hv.y * w1.x + hv.z * w2.x + hv.w * w3.x;
            acc.y += hv.x * w0.y + hv.y * w1.y + hv.z * w2.y + hv.w * w3.y;
            acc.z += hv.x * w0.z + hv.y * w1.z + hv.z * w2.z + hv.w * w3.z;
            acc.w += hv.x * w0.w + hv.y * w1.w + hv.z * w2.w + hv.w * w3.w;
        }
    }
    {
        __syncthreads();
        for (int u = 0; u < 32; u++) {
            int f4 = u * 256 + tid;
            int rr = f4 >> 8;
            int kq = (f4 & 255) << 2;
            *reinterpret_cast<float4*>(&hs[rr * 1028 + kq]) =
                *reinterpret_cast<const float4*>(X + ((size_t)rr * 512 + t) * 1024 + kq);
        }
        __syncthreads();
        const float* Wg = (gate == 0) ? Wax : ((gate == 1) ? Wix : ((gate == 2) ? Wfx : Wox));
        const float* Wp = Wg + hc0;
#pragma unroll 4
        for (int k = k0; k < k0 + 512; k += 4) {
            float4 hv = *reinterpret_cast<const float4*>(&hs[r * 1028 + k]);
            float4 w0 = *reinterpret_cast<const float4*>(Wp + (size_t)(k + 0) * 1024);
            float4 w1 = *reinterpret_cast<const float4*>(Wp + (size_t)(k + 1) * 1024);
            float4 w2 = *reinterpret_cast<const float4*>(Wp + (size_t)(k + 2) * 1024);
            float4 w3 = *reinterpret_cast<const float4*>(Wp + (size_t)(k + 3) * 1024);
            acc.x += hv.x * w0.x + hv.y * w1.x + hv.z * w2.x + hv.w * w3.x;
            acc.y += hv.x * w0.y + hv.y * w1.y + hv.z * w2.y + hv.w * w3.y;
            acc.z += hv.x * w0.z + hv.y * w1.z + hv.z * w2.z + hv.w * w3.z;
            acc.w += hv.x * w0.w + hv.y * w1.w + hv.z * w2.w + hv.w * w3.w;
        }
    }

    *reinterpret_cast<float4*>(&gs[kh][r][gate * 4]) = acc;
    __syncthreads();

    if (tid < 128) {
        const int rr = tid >> 2;
        const int hcl = tid & 3;
        const int h  = hc0 + hcl;
        float ga = gs[0][rr][0 + hcl]  + gs[1][rr][0 + hcl]  + ba[h];
        float gi = gs[0][rr][4 + hcl]  + gs[1][rr][4 + hcl]  + bi[h];
        float gf = gs[0][rr][8 + hcl]  + gs[1][rr][8 + hcl]  + bfv[h];
        float gO = gs[0][rr][12 + hcl] + gs[1][rr][12 + hcl] + bo[h];
        float a = tanh_f(ga);
        float i = sigm_f(gi);
        float f = sigm_f(gf);
        float o = sigm_f(gO);
        float sprev = FIRST ? 0.f : sbuf[rr * 1024 + h];
        float s = a * i + sprev * f;
        sbuf[rr * 1024 + h] = s;
        float hv = tanh_f(s) * o;
        hnext[rr * 1024 + h] = hv;
        out[((size_t)rr * 512 + t) * 1024 + h] = hv;
    }
}

extern "C" void kernel_launch(void* const* d_in, const int* in_sizes, int n_in,
                              void* d_out, int out_size, void* d_ws, size_t ws_size,
                              hipStream_t stream)
{
    const float* X   = (const float*)d_in[0];
    const float* Wax = (const float*)d_in[1];
    const float* Wix = (const float*)d_in[2];
    const float* Wfx = (const float*)d_in[3];
    const float* Wox = (const float*)d_in[4];
    const float* Wah = (const float*)d_in[5];
    const float* Wih = (const float*)d_in[6];
    const float* Wfh = (const float*)d_in[7];
    const float* Woh = (const float*)d_in[8];
    const float* ba  = (const float*)d_in[9];
    const float* bi  = (const float*)d_in[10];
    const float* bfv = (const float*)d_in[11];
    const float* bo  = (const float*)d_in[12];
    float* out = (float*)d_out;

    const size_t XGH  = (size_t)512 * 32 * 4096 * 2;      // 128 MiB fp16 xg
    const size_t WPK  = (size_t)256 * 16384 * 2;          // 8 MiB fp16 packed Wh
    const size_t WTX  = (size_t)4096 * 1024 * 2;          // 8 MiB fp16 Wt
    const size_t XHH  = (size_t)16384 * 1024 * 2;         // 32 MiB fp16 Xh
    const size_t H32  = (size_t)32 * 1024 * 4;            // 128 KiB tagged h
    const size_t HBF  = (size_t)32 * 1024 * 4;

    char* ws = (char*)d_ws;
    const bool big = ws_size >= XGH + WPK + WTX + XHH + 2 * H32;

    if (big) {
        unsigned short* xg   = (unsigned short*)ws;
        unsigned short* wpk  = (unsigned short*)(ws + XGH);
        unsigned short* Wt   = (unsigned short*)(ws + XGH + WPK);
        unsigned short* Xh   = (unsigned short*)(ws + XGH + WPK + WTX);
        unsigned*       h32A = (unsigned*)(ws + XGH + WPK + WTX + XHH);
        unsigned*       h32B = (unsigned*)(ws + XGH + WPK + WTX + XHH + H32);

        // clear stale tags (graph replays) — stream-ordered before lstm_persist
        hipMemsetAsync(h32A, 0, 2 * H32, stream);
        wtrans_kernel<<<1024, 256, 0, stream>>>(Wax, Wix, Wfx, Wox, Wt);
        xcvt_kernel<<<8192, 256, 0, stream>>>(X, Xh);
        proj_mfma<<<4096, 256, 0, stream>>>((const _Float16*)Xh, (const _Float16*)Wt, xg);

        const unsigned short* xgu = xg;
        void* args[] = {
            (void*)&xgu,
            (void*)&Wah, (void*)&Wih, (void*)&Wfh, (void*)&Woh,
            (void*)&ba, (void*)&bi, (void*)&bfv, (void*)&bo,
            (void*)&wpk, (void*)&h32A, (void*)&h32B, (void*)&out
        };
        hipLaunchCooperativeKernel((void*)lstm_persist, dim3(256), dim3(512),
                                   args, 0, stream);
    } else {
        float* h0 = (float*)ws;
        float* h1 = (float*)(ws + HBF);
        float* sb = (float*)(ws + 2 * HBF);
        float* hb[2] = { h0, h1 };
        for (int t = 0; t < 512; ++t) {
            const float* hprev = hb[(t + 1) & 1];
            float* hnext = hb[t & 1];
            if (t == 0)
                step_kernel<true><<<256, 256, 0, stream>>>(hprev, hnext, sb, X,
                    Wah, Wih, Wfh, Woh, Wax, Wix, Wfx, Wox, ba, bi, bfv, bo, out, t);
            else
                step_kernel<false><<<256, 256, 0, stream>>>(hprev, hnext, sb, X,
                    Wah, Wih, Wfh, Woh, Wax, Wix, Wfx, Wox, ba, bi, bfv, bo, out, t);
        }
    }
}

// Round 8
// 3308.220 us; speedup vs baseline: 1.3241x; 1.3241x over previous
//
#include <hip/hip_runtime.h>
#include <hip/hip_fp16.h>

// LSTM: B=32, T=512, D=1024, H=1024.
// wtrans ; xcvt ; proj (fp16 MFMA) ; persistent recurrent kernel (round-4
// structure, validated 1758us) with ONE change: the flat 256-flag barrier is
// replaced by a single per-step arrival counter (atomicAdd + 1-thread poll),
// cutting poll-phase IC contention ~256x.

typedef __attribute__((ext_vector_type(8))) _Float16 f16x8;
typedef __attribute__((ext_vector_type(8))) short    short8;
typedef __attribute__((ext_vector_type(4))) float    f32x4;

__device__ __forceinline__ float sigm_f(float x) { return 1.0f / (1.0f + __expf(-x)); }
__device__ __forceinline__ float tanh_f(float x) { return 1.0f - 2.0f / (__expf(2.0f * x) + 1.0f); }

__device__ __forceinline__ void ld_sys_b128(short8& d, const void* p) {
    asm volatile("global_load_dwordx4 %0, %1, off sc0 sc1" : "=v"(d) : "v"(p) : "memory");
}
__device__ __forceinline__ void st_sys_u16(void* p, unsigned v) {
    asm volatile("global_store_short %0, %1, off sc0 sc1" :: "v"(p), "v"(v) : "memory");
}

// ---------------- X -> fp16 ----------------
__global__ __launch_bounds__(256)
void xcvt_kernel(const float* __restrict__ X, unsigned short* __restrict__ Xh)
{
    int i = blockIdx.x * 256 + threadIdx.x;
    float4 v0 = *reinterpret_cast<const float4*>(X + (size_t)i * 8);
    float4 v1 = *reinterpret_cast<const float4*>(X + (size_t)i * 8 + 4);
    unsigned short o[8];
    o[0] = __half_as_ushort(__float2half_rn(v0.x));
    o[1] = __half_as_ushort(__float2half_rn(v0.y));
    o[2] = __half_as_ushort(__float2half_rn(v0.z));
    o[3] = __half_as_ushort(__float2half_rn(v0.w));
    o[4] = __half_as_ushort(__float2half_rn(v1.x));
    o[5] = __half_as_ushort(__float2half_rn(v1.y));
    o[6] = __half_as_ushort(__float2half_rn(v1.z));
    o[7] = __half_as_ushort(__float2half_rn(v1.w));
    *reinterpret_cast<int4*>(Xh + (size_t)i * 8) = *reinterpret_cast<int4*>(o);
}

// ---------------- W transpose + fp16 convert ----------------
__global__ __launch_bounds__(256)
void wtrans_kernel(const float* __restrict__ Wa, const float* __restrict__ Wi,
                   const float* __restrict__ Wf, const float* __restrict__ Wo,
                   unsigned short* __restrict__ Wt)
{
    __shared__ float Ts[64][65];
    const int bx = blockIdx.x;
    const int g  = bx >> 8;
    const int k0 = ((bx >> 4) & 15) * 64;
    const int c0 = (bx & 15) * 64;
    const float* W = (g == 0) ? Wa : ((g == 1) ? Wi : ((g == 2) ? Wf : Wo));
    const int tid = threadIdx.x;
#pragma unroll
    for (int u = 0; u < 4; ++u) {
        int r  = u * 16 + (tid >> 4);
        int c4 = (tid & 15) * 4;
        float4 v = *reinterpret_cast<const float4*>(W + (size_t)(k0 + r) * 1024 + c0 + c4);
        Ts[r][c4 + 0] = v.x; Ts[r][c4 + 1] = v.y; Ts[r][c4 + 2] = v.z; Ts[r][c4 + 3] = v.w;
    }
    __syncthreads();
#pragma unroll
    for (int u = 0; u < 4; ++u) {
        int col = u * 16 + (tid >> 4);
        int k4  = (tid & 15) * 4;
        unsigned short o[4];
#pragma unroll
        for (int j = 0; j < 4; ++j)
            o[j] = __half_as_ushort(__float2half_rn(Ts[k4 + j][col]));
        *reinterpret_cast<ushort4*>(Wt + ((size_t)g * 1024 + c0 + col) * 1024 + k0 + k4) =
            *reinterpret_cast<ushort4*>(o);
    }
}

// ---------------- Projection GEMM via fp16 MFMA ----------------
__global__ __launch_bounds__(256)
void proj_mfma(const _Float16* __restrict__ Xh,
               const _Float16* __restrict__ Wt,
               unsigned short* __restrict__ xg)
{
    __shared__ _Float16 As[128 * 40];
    __shared__ _Float16 Bs[128 * 40];

    const int tid  = threadIdx.x;
    const int bn   = blockIdx.x & 31;
    const int bm   = blockIdx.x >> 5;
    const int row0 = bm * 128, col0 = bn * 128;
    const int w    = tid >> 6, lane = tid & 63;
    const int wm   = w >> 1,  wn   = w & 1;
    const int lr   = lane & 15, ko = lane >> 4;

    f32x4 acc[4][4];
#pragma unroll
    for (int mi = 0; mi < 4; ++mi)
#pragma unroll
        for (int ni = 0; ni < 4; ++ni)
            acc[mi][ni] = f32x4{0.f, 0.f, 0.f, 0.f};

    for (int kt = 0; kt < 1024; kt += 32) {
#pragma unroll
        for (int u = 0; u < 2; ++u) {
            int i8  = u * 256 + tid;
            int r   = i8 >> 2, k8 = (i8 & 3) * 8;
            *reinterpret_cast<float4*>(&As[r * 40 + k8]) =
                *reinterpret_cast<const float4*>(Xh + (size_t)(row0 + r) * 1024 + kt + k8);
        }
#pragma unroll
        for (int u = 0; u < 2; ++u) {
            int i8  = u * 256 + tid;
            int col = i8 >> 2, k8 = (i8 & 3) * 8;
            *reinterpret_cast<float4*>(&Bs[col * 40 + k8]) =
                *reinterpret_cast<const float4*>(Wt + (size_t)(col0 + col) * 1024 + kt + k8);
        }
        __syncthreads();

        f16x8 af[4], bf[4];
#pragma unroll
        for (int mi = 0; mi < 4; ++mi)
            af[mi] = *reinterpret_cast<const f16x8*>(&As[(wm * 64 + mi * 16 + lr) * 40 + ko * 8]);
#pragma unroll
        for (int ni = 0; ni < 4; ++ni)
            bf[ni] = *reinterpret_cast<const f16x8*>(&Bs[(wn * 64 + ni * 16 + lr) * 40 + ko * 8]);
#pragma unroll
        for (int mi = 0; mi < 4; ++mi)
#pragma unroll
            for (int ni = 0; ni < 4; ++ni)
                acc[mi][ni] = __builtin_amdgcn_mfma_f32_16x16x32_f16(af[mi], bf[ni], acc[mi][ni], 0, 0, 0);
        __syncthreads();
    }

#pragma unroll
    for (int mi = 0; mi < 4; ++mi)
#pragma unroll
        for (int ni = 0; ni < 4; ++ni)
#pragma unroll
            for (int j = 0; j < 4; ++j) {
                int rt = row0 + wm * 64 + mi * 16 + ko * 4 + j;
                int ct = col0 + wn * 64 + ni * 16 + lr;
                int b = rt >> 9, t = rt & 511;
                xg[((size_t)t * 32 + b) * 4096 + ct] =
                    __half_as_ushort(__float2half_rn(acc[mi][ni][j]));
            }
}

// ---------------- Persistent MFMA recurrent kernel: 256 blocks ----------------
// Round-4 structure (validated 1758us). Block blk owns h-cols [blk*4, blk*4+4)
// -> 16 gate-cols. 8 waves, K-split 8. Per step: S1 (drain h sc-stores) ->
// counter publish + xg stage + 1-thread poll -> S2 -> a sc-loads + MFMA ->
// pbuf -> S3 -> reduce -> gbuf -> S4 -> gates + h/out store.
__global__ __launch_bounds__(512)
void lstm_persist(const unsigned short* __restrict__ xg,   // [512][32][4096] fp16
                  const float* __restrict__ Wah, const float* __restrict__ Wih,
                  const float* __restrict__ Wfh, const float* __restrict__ Woh,
                  const float* __restrict__ ba, const float* __restrict__ bi,
                  const float* __restrict__ bfv, const float* __restrict__ bo,
                  unsigned short* __restrict__ wpk,        // [256][16384] fp16 B-frag order
                  unsigned short* __restrict__ h16A,       // [128][32][8] fp16
                  unsigned short* __restrict__ h16B,
                  unsigned* __restrict__ ctr,              // [512] arrival counters, pre-zeroed
                  float* __restrict__ out)                 // [32][512][1024]
{
    __shared__ float pbuf[16 * 64 * 4];
    __shared__ float gbuf[32 * 16];
    __shared__ unsigned short xbuf[32][16];

    const int tid  = threadIdx.x;
    const int blk  = blockIdx.x;
    const int hc0  = blk * 4;
    const int wv   = tid >> 6;
    const int lane = tid & 63;

    // pack Wh slice into B-fragment order (fp16), once
    unsigned short* wb = wpk + (size_t)blk * 16384;
#pragma unroll
    for (int q = 0; q < 4; ++q) {
        int fq    = tid * 4 + q;
        int kiter = fq >> 6;
        int ln    = fq & 63;
        int col   = ln & 15;
        int g     = col >> 2, c = col & 3;
        int kbase = kiter * 32 + (ln >> 4) * 8;
        const float* Wg = (g == 0) ? Wah : ((g == 1) ? Wih : ((g == 2) ? Wfh : Woh));
        unsigned short tmp[8];
#pragma unroll
        for (int e = 0; e < 8; ++e)
            tmp[e] = __half_as_ushort(__float2half_rn(Wg[(size_t)(kbase + e) * 1024 + hc0 + c]));
        *reinterpret_cast<int4*>(wb + (size_t)fq * 8) = *reinterpret_cast<int4*>(tmp);
    }

    float biasr[4][4];
    float sreg = 0.f;
    if (tid < 128) {
        int hc = tid & 3;
        biasr[0][hc] = ba [hc0 + hc];
        biasr[1][hc] = bi [hc0 + hc];
        biasr[2][hc] = bfv[hc0 + hc];
        biasr[3][hc] = bo [hc0 + hc];
    }

    __syncthreads();

    const int koct = lane >> 4;
    const int arow = lane & 15;

    for (int t = 0; t < 512; ++t) {
        if (t > 0) {
            __syncthreads();                               // S1: h sc-stores drained (vmcnt0/wave)
            if (tid == 0)
                atomicAdd(&ctr[t], 1u);                    // fire-and-forget, executes at IC
            if (tid < 128) {                               // overlap: xg tile for step t
                int r = tid >> 2, g = tid & 3;
                ushort4 v = *reinterpret_cast<const ushort4*>(
                    xg + ((size_t)t * 32 + r) * 4096 + g * 1024 + hc0);
                *reinterpret_cast<ushort4*>(&xbuf[r][g * 4]) = v;
            }
            if (tid == 0) {
                while (__hip_atomic_load(&ctr[t], __ATOMIC_RELAXED, __HIP_MEMORY_SCOPE_AGENT) < 256u)
                    __builtin_amdgcn_s_sleep(1);
            }
            __syncthreads();                               // S2: all blocks arrived
        } else {
            if (tid < 128) {
                int r = tid >> 2, g = tid & 3;
                ushort4 v = *reinterpret_cast<const ushort4*>(
                    xg + ((size_t)r * 4096) + g * 1024 + hc0);
                *reinterpret_cast<ushort4*>(&xbuf[r][g * 4]) = v;
            }
        }

        const unsigned short* hp = (t & 1) ? h16A : h16B;
        unsigned short*       hn = (t & 1) ? h16B : h16A;

        if (t > 0) {
            short8 a0[4], a1[4], b[4];
#pragma unroll
            for (int ki = 0; ki < 4; ++ki) {
                int kit = wv * 4 + ki;
                b[ki] = *reinterpret_cast<const short8*>(wb + ((size_t)(kit * 64 + lane) * 8));
            }
#pragma unroll
            for (int ki = 0; ki < 4; ++ki) {
                int kit = wv * 4 + ki;
                int oct = kit * 4 + koct;
                ld_sys_b128(a0[ki], hp + ((size_t)(oct * 32 + arow) * 8));
                ld_sys_b128(a1[ki], hp + ((size_t)(oct * 32 + arow + 16) * 8));
            }
            asm volatile("s_waitcnt vmcnt(0)" ::: "memory");
            __builtin_amdgcn_sched_barrier(0);

            f32x4 acc0 = {0.f, 0.f, 0.f, 0.f};
            f32x4 acc1 = {0.f, 0.f, 0.f, 0.f};
#pragma unroll
            for (int ki = 0; ki < 4; ++ki) {
                acc0 = __builtin_amdgcn_mfma_f32_16x16x32_f16(
                    __builtin_bit_cast(f16x8, a0[ki]), __builtin_bit_cast(f16x8, b[ki]), acc0, 0, 0, 0);
                acc1 = __builtin_amdgcn_mfma_f32_16x16x32_f16(
                    __builtin_bit_cast(f16x8, a1[ki]), __builtin_bit_cast(f16x8, b[ki]), acc1, 0, 0, 0);
            }
            *reinterpret_cast<f32x4*>(&pbuf[((wv * 2 + 0) * 64 + lane) * 4]) = acc0;
            *reinterpret_cast<f32x4*>(&pbuf[((wv * 2 + 1) * 64 + lane) * 4]) = acc1;
        }
        __syncthreads();                                   // S3: partials visible

        if (t > 0) {
            int m  = tid >> 8;
            int ln = (tid >> 2) & 63;
            int rg = tid & 3;
            float s = 0.f;
#pragma unroll
            for (int w = 0; w < 8; ++w)
                s += pbuf[((w * 2 + m) * 64 + ln) * 4 + rg];
            int row = m * 16 + (ln >> 4) * 4 + rg;
            int col = ln & 15;
            gbuf[row * 16 + col] = s;
        }
        __syncthreads();                                   // S4: g matrix reduced

        if (tid < 128) {
            const int row = tid >> 2;
            const int hc  = tid & 3;
            float ga = (t > 0 ? gbuf[row * 16 + 0 * 4 + hc] : 0.f) + biasr[0][hc]
                     + __half2float(__ushort_as_half(xbuf[row][0 * 4 + hc]));
            float gi = (t > 0 ? gbuf[row * 16 + 1 * 4 + hc] : 0.f) + biasr[1][hc]
                     + __half2float(__ushort_as_half(xbuf[row][1 * 4 + hc]));
            float gf = (t > 0 ? gbuf[row * 16 + 2 * 4 + hc] : 0.f) + biasr[2][hc]
                     + __half2float(__ushort_as_half(xbuf[row][2 * 4 + hc]));
            float gO = (t > 0 ? gbuf[row * 16 + 3 * 4 + hc] : 0.f) + biasr[3][hc]
                     + __half2float(__ushort_as_half(xbuf[row][3 * 4 + hc]));
            float a  = tanh_f(ga);
            float ii = sigm_f(gi);
            float ff = sigm_f(gf);
            float oo = sigm_f(gO);
            sreg = a * ii + sreg * ff;
            float hv = tanh_f(sreg) * oo;

            int colg = hc0 + hc;
            st_sys_u16(hn + ((size_t)(colg >> 3) * 32 + row) * 8 + (colg & 7),
                       (unsigned)__half_as_ushort(__float2half_rn(hv)));
            out[((size_t)row * 512 + t) * 1024 + colg] = hv;
        }
    }
}

// ---------------- Fallback per-step kernel (fp32) ----------------
template<bool FIRST>
__global__ __launch_bounds__(256)
void step_kernel(const float* __restrict__ hprev, float* __restrict__ hnext,
                 float* __restrict__ sbuf, const float* __restrict__ X,
                 const float* __restrict__ Wah, const float* __restrict__ Wih,
                 const float* __restrict__ Wfh, const float* __restrict__ Woh,
                 const float* __restrict__ Wax, const float* __restrict__ Wix,
                 const float* __restrict__ Wfx, const float* __restrict__ Wox,
                 const float* __restrict__ ba, const float* __restrict__ bi,
                 const float* __restrict__ bfv, const float* __restrict__ bo,
                 float* __restrict__ out, int t)
{
    __shared__ float hs[32 * 1028];
    __shared__ float gs[2][32][16];

    const int tid  = threadIdx.x;
    const int hc0  = blockIdx.x * 4;
    const int kh   = tid >> 7;
    const int gtid = tid & 127;
    const int r    = gtid >> 2;
    const int gate = gtid & 3;
    const int k0   = kh * 512;

    float4 acc = make_float4(0.f, 0.f, 0.f, 0.f);

    if (!FIRST) {
        for (int u = 0; u < 32; u++) {
            int f4 = u * 256 + tid;
            int rr = f4 >> 8;
            int kq = (f4 & 255) << 2;
            *reinterpret_cast<float4*>(&hs[rr * 1028 + kq]) =
                *reinterpret_cast<const float4*>(hprev + rr * 1024 + kq);
        }
        __syncthreads();
        const float* Wg = (gate == 0) ? Wah : ((gate == 1) ? Wih : ((gate == 2) ? Wfh : Woh));
        const float* Wp = Wg + hc0;
#pragma unroll 4
        for (int k = k0; k < k0 + 512; k += 4) {
            float4 hv = *reinterpret_cast<const float4*>(&hs[r * 1028 + k]);
            float4 w0 = *reinterpret_cast<const float4*>(Wp + (size_t)(k + 0) * 1024);
            float4 w1 = *reinterpret_cast<const float4*>(Wp + (size_t)(k + 1) * 1024);
            float4 w2 = *reinterpret_cast<const float4*>(Wp + (size_t)(k + 2) * 1024);
            float4 w3 = *reinterpret_cast<const float4*>(Wp + (size_t)(k + 3) * 1024);
            acc.x += hv.x * w0.x + hv.y * w1.x + hv.z * w2.x + hv.w * w3.x;
            acc.y += hv.x * w0.y + hv.y * w1.y + hv.z * w2.y + hv.w * w3.y;
            acc.z += hv.x * w0.z + hv.y * w1.z + hv.z * w2.z + hv.w * w3.z;
            acc.w += hv.x * w0.w + hv.y * w1.w + hv.z * w2.w + hv.w * w3.w;
        }
    }
    {
        __syncthreads();
        for (int u = 0; u < 32; u++) {
            int f4 = u * 256 + tid;
            int rr = f4 >> 8;
            int kq = (f4 & 255) << 2;
            *reinterpret_cast<float4*>(&hs[rr * 1028 + kq]) =
                *reinterpret_cast<const float4*>(X + ((size_t)rr * 512 + t) * 1024 + kq);
        }
        __syncthreads();
        const float* Wg = (gate == 0) ? Wax : ((gate == 1) ? Wix : ((gate == 2) ? Wfx : Wox));
        const float* Wp = Wg + hc0;
#pragma unroll 4
        for (int k = k0; k < k0 + 512; k += 4) {
            float4 hv = *reinterpret_cast<const float4*>(&hs[r * 1028 + k]);
            float4 w0 = *reinterpret_cast<const float4*>(Wp + (size_t)(k + 0) * 1024);
            float4 w1 = *reinterpret_cast<const float4*>(Wp + (size_t)(k + 1) * 1024);
            float4 w2 = *reinterpret_cast<const float4*>(Wp + (size_t)(k + 2) * 1024);
            float4 w3 = *reinterpret_cast<const float4*>(Wp + (size_t)(k + 3) * 1024);
            acc.x += hv.x * w0.x + hv.y * w1.x + hv.z * w2.x + hv.w * w3.x;
            acc.y += hv.x * w0.y + hv.y * w1.y + hv.z * w2.y + hv.w * w3.y;
            acc.z += hv.x * w0.z + hv.y * w1.z + hv.z * w2.z + hv.w * w3.z;
            acc.w += hv.x * w0.w + hv.y * w1.w + hv.z * w2.w + hv.w * w3.w;
        }
    }

    *reinterpret_cast<float4*>(&gs[kh][r][gate * 4]) = acc;
    __syncthreads();

    if (tid < 128) {
        const int rr = tid >> 2;
        const int hcl = tid & 3;
        const int h  = hc0 + hcl;
        float ga = gs[0][rr][0 + hcl]  + gs[1][rr][0 + hcl]  + ba[h];
        float gi = gs[0][rr][4 + hcl]  + gs[1][rr][4 + hcl]  + bi[h];
        float gf = gs[0][rr][8 + hcl]  + gs[1][rr][8 + hcl]  + bfv[h];
        float gO = gs[0][rr][12 + hcl] + gs[1][rr][12 + hcl] + bo[h];
        float a = tanh_f(ga);
        float i = sigm_f(gi);
        float f = sigm_f(gf);
        float o = sigm_f(gO);
        float sprev = FIRST ? 0.f : sbuf[rr * 1024 + h];
        float s = a * i + sprev * f;
        sbuf[rr * 1024 + h] = s;
        float hv = tanh_f(s) * o;
        hnext[rr * 1024 + h] = hv;
        out[((size_t)rr * 512 + t) * 1024 + h] = hv;
    }
}

extern "C" void kernel_launch(void* const* d_in, const int* in_sizes, int n_in,
                              void* d_out, int out_size, void* d_ws, size_t ws_size,
                              hipStream_t stream)
{
    const float* X   = (const float*)d_in[0];
    const float* Wax = (const float*)d_in[1];
    const float* Wix = (const float*)d_in[2];
    const float* Wfx = (const float*)d_in[3];
    const float* Wox = (const float*)d_in[4];
    const float* Wah = (const float*)d_in[5];
    const float* Wih = (const float*)d_in[6];
    const float* Wfh = (const float*)d_in[7];
    const float* Woh = (const float*)d_in[8];
    const float* ba  = (const float*)d_in[9];
    const float* bi  = (const float*)d_in[10];
    const float* bfv = (const float*)d_in[11];
    const float* bo  = (const float*)d_in[12];
    float* out = (float*)d_out;

    const size_t XGH  = (size_t)512 * 32 * 4096 * 2;      // 128 MiB fp16 xg
    const size_t WPK  = (size_t)256 * 16384 * 2;          // 8 MiB fp16 packed Wh
    const size_t WTX  = (size_t)4096 * 1024 * 2;          // 8 MiB fp16 Wt
    const size_t XHH  = (size_t)16384 * 1024 * 2;         // 32 MiB fp16 Xh
    const size_t H16  = (size_t)32 * 1024 * 2;            // 64 KiB fp16 h
    const size_t BAR  = 4096;                              // ctr[512] + pad
    const size_t HBF  = (size_t)32 * 1024 * 4;

    char* ws = (char*)d_ws;
    const bool big = ws_size >= XGH + WPK + WTX + XHH + 2 * H16 + BAR;

    if (big) {
        unsigned short* xg    = (unsigned short*)ws;
        unsigned short* wpk   = (unsigned short*)(ws + XGH);
        unsigned short* Wt    = (unsigned short*)(ws + XGH + WPK);
        unsigned short* Xh    = (unsigned short*)(ws + XGH + WPK + WTX);
        unsigned short* h16A  = (unsigned short*)(ws + XGH + WPK + WTX + XHH);
        unsigned short* h16B  = (unsigned short*)(ws + XGH + WPK + WTX + XHH + H16);
        unsigned*       ctr   = (unsigned*)(ws + XGH + WPK + WTX + XHH + 2 * H16);

        hipMemsetAsync(ctr, 0, BAR, stream);
        wtrans_kernel<<<1024, 256, 0, stream>>>(Wax, Wix, Wfx, Wox, Wt);
        xcvt_kernel<<<8192, 256, 0, stream>>>(X, Xh);
        proj_mfma<<<4096, 256, 0, stream>>>((const _Float16*)Xh, (const _Float16*)Wt, xg);

        const unsigned short* xgu = xg;
        void* args[] = {
            (void*)&xgu,
            (void*)&Wah, (void*)&Wih, (void*)&Wfh, (void*)&Woh,
            (void*)&ba, (void*)&bi, (void*)&bfv, (void*)&bo,
            (void*)&wpk, (void*)&h16A, (void*)&h16B,
            (void*)&ctr, (void*)&out
        };
        hipLaunchCooperativeKernel((void*)lstm_persist, dim3(256), dim3(512),
                                   args, 0, stream);
    } else {
        float* h0 = (float*)ws;
        float* h1 = (float*)(ws + HBF);
        float* sb = (float*)(ws + 2 * HBF);
        float* hb[2] = { h0, h1 };
        for (int t = 0; t < 512; ++t) {
            const float* hprev = hb[(t + 1) & 1];
            float* hnext = hb[t & 1];
            if (t == 0)
                step_kernel<true><<<256, 256, 0, stream>>>(hprev, hnext, sb, X,
                    Wah, Wih, Wfh, Woh, Wax, Wix, Wfx, Wox, ba, bi, bfv, bo, out, t);
            else
                step_kernel<false><<<256, 256, 0, stream>>>(hprev, hnext, sb, X,
                    Wah, Wih, Wfh, Woh, Wax, Wix, Wfx, Wox, ba, bi, bfv, bo, out, t);
        }
    }
}

// Round 11
// 2262.729 us; speedup vs baseline: 1.9359x; 1.4620x over previous
//
#include <hip/hip_runtime.h>
#include <hip/hip_fp16.h>

// LSTM: B=32, T=512, D=1024, H=1024.
// Round-4 structure + CORRECT race fix: h published via atomicExch WITH
// CONSUMED RETURN VALUE. vmcnt for a returning atomic decrements only when the
// old-value response arrives (i.e., the RMW executed at the Infinity Cache),
// so S1's pre-barrier vmcnt(0) now truly guarantees h-at-IC before the flag
// is published. Rounds 3-10 used fire-and-forget publishes whose vmcnt ack
// only meant "data left the VGPRs" -> rare stale-h reads (rounds 9/10 fails).

typedef __attribute__((ext_vector_type(8))) _Float16 f16x8;
typedef __attribute__((ext_vector_type(8))) short    short8;
typedef __attribute__((ext_vector_type(4))) float    f32x4;

__device__ __forceinline__ float sigm_f(float x) { return 1.0f / (1.0f + __expf(-x)); }
__device__ __forceinline__ float tanh_f(float x) { return 1.0f - 2.0f / (__expf(2.0f * x) + 1.0f); }

__device__ __forceinline__ void ld_sys_b128(short8& d, const void* p) {
    asm volatile("global_load_dwordx4 %0, %1, off sc0 sc1" : "=v"(d) : "v"(p) : "memory");
}

// ---------------- W transpose + fp16 convert ----------------
__global__ __launch_bounds__(256)
void wtrans_kernel(const float* __restrict__ Wa, const float* __restrict__ Wi,
                   const float* __restrict__ Wf, const float* __restrict__ Wo,
                   unsigned short* __restrict__ Wt)
{
    __shared__ float Ts[64][65];
    const int bx = blockIdx.x;
    const int g  = bx >> 8;
    const int k0 = ((bx >> 4) & 15) * 64;
    const int c0 = (bx & 15) * 64;
    const float* W = (g == 0) ? Wa : ((g == 1) ? Wi : ((g == 2) ? Wf : Wo));
    const int tid = threadIdx.x;
#pragma unroll
    for (int u = 0; u < 4; ++u) {
        int r  = u * 16 + (tid >> 4);
        int c4 = (tid & 15) * 4;
        float4 v = *reinterpret_cast<const float4*>(W + (size_t)(k0 + r) * 1024 + c0 + c4);
        Ts[r][c4 + 0] = v.x; Ts[r][c4 + 1] = v.y; Ts[r][c4 + 2] = v.z; Ts[r][c4 + 3] = v.w;
    }
    __syncthreads();
#pragma unroll
    for (int u = 0; u < 4; ++u) {
        int col = u * 16 + (tid >> 4);
        int k4  = (tid & 15) * 4;
        unsigned short o[4];
#pragma unroll
        for (int j = 0; j < 4; ++j)
            o[j] = __half_as_ushort(__float2half_rn(Ts[k4 + j][col]));
        *reinterpret_cast<ushort4*>(Wt + ((size_t)g * 1024 + c0 + col) * 1024 + k0 + k4) =
            *reinterpret_cast<ushort4*>(o);
    }
}

// ---------------- Projection GEMM via fp16 MFMA ----------------
__global__ __launch_bounds__(256)
void proj_mfma(const float* __restrict__ X,
               const _Float16* __restrict__ Wt,
               unsigned short* __restrict__ xg)
{
    __shared__ _Float16 As[128 * 40];
    __shared__ _Float16 Bs[128 * 40];

    const int tid  = threadIdx.x;
    const int bn   = blockIdx.x & 31;
    const int bm   = blockIdx.x >> 5;
    const int row0 = bm * 128, col0 = bn * 128;
    const int w    = tid >> 6, lane = tid & 63;
    const int wm   = w >> 1,  wn   = w & 1;
    const int lr   = lane & 15, ko = lane >> 4;

    f32x4 acc[4][4];
#pragma unroll
    for (int mi = 0; mi < 4; ++mi)
#pragma unroll
        for (int ni = 0; ni < 4; ++ni)
            acc[mi][ni] = f32x4{0.f, 0.f, 0.f, 0.f};

    for (int kt = 0; kt < 1024; kt += 32) {
#pragma unroll
        for (int u = 0; u < 4; ++u) {
            int f4 = u * 256 + tid;
            int r  = f4 >> 3, kq = (f4 & 7) * 4;
            float4 v = *reinterpret_cast<const float4*>(X + (size_t)(row0 + r) * 1024 + kt + kq);
            _Float16 h4[4] = {(_Float16)v.x, (_Float16)v.y, (_Float16)v.z, (_Float16)v.w};
            *reinterpret_cast<double*>(&As[r * 40 + kq]) = *reinterpret_cast<double*>(h4);
        }
#pragma unroll
        for (int u = 0; u < 2; ++u) {
            int i8  = u * 256 + tid;
            int col = i8 >> 2, k8 = (i8 & 3) * 8;
            *reinterpret_cast<float4*>(&Bs[col * 40 + k8]) =
                *reinterpret_cast<const float4*>(Wt + (size_t)(col0 + col) * 1024 + kt + k8);
        }
        __syncthreads();

        f16x8 af[4], bf[4];
#pragma unroll
        for (int mi = 0; mi < 4; ++mi)
            af[mi] = *reinterpret_cast<const f16x8*>(&As[(wm * 64 + mi * 16 + lr) * 40 + ko * 8]);
#pragma unroll
        for (int ni = 0; ni < 4; ++ni)
            bf[ni] = *reinterpret_cast<const f16x8*>(&Bs[(wn * 64 + ni * 16 + lr) * 40 + ko * 8]);
#pragma unroll
        for (int mi = 0; mi < 4; ++mi)
#pragma unroll
            for (int ni = 0; ni < 4; ++ni)
                acc[mi][ni] = __builtin_amdgcn_mfma_f32_16x16x32_f16(af[mi], bf[ni], acc[mi][ni], 0, 0, 0);
        __syncthreads();
    }

#pragma unroll
    for (int mi = 0; mi < 4; ++mi)
#pragma unroll
        for (int ni = 0; ni < 4; ++ni)
#pragma unroll
            for (int j = 0; j < 4; ++j) {
                int rt = row0 + wm * 64 + mi * 16 + ko * 4 + j;
                int ct = col0 + wn * 64 + ni * 16 + lr;
                int b = rt >> 9, t = rt & 511;
                xg[((size_t)t * 32 + b) * 4096 + ct] =
                    __half_as_ushort(__float2half_rn(acc[mi][ni][j]));
            }
}

// ---------------- Persistent MFMA recurrent kernel ----------------
// 256 blocks x 512 threads (cooperative). Block owns h-cols [blk*4,+4) = 16 gate-cols.
// Flat flag barrier; xg tile staged during poll window; h published via
// atomicExch WITH RETURN (ack == executed at IC). Readers sc0/sc1.
__global__ __launch_bounds__(512)
void lstm_persist(const unsigned short* __restrict__ xg,   // [512][32][4096] fp16
                  const float* __restrict__ Wah, const float* __restrict__ Wih,
                  const float* __restrict__ Wfh, const float* __restrict__ Woh,
                  const float* __restrict__ ba, const float* __restrict__ bi,
                  const float* __restrict__ bfv, const float* __restrict__ bo,
                  unsigned short* __restrict__ wpk,        // [256][16384] fp16 B-frag order
                  unsigned short* __restrict__ h16A,       // [128][32][8] fp16
                  unsigned short* __restrict__ h16B,
                  unsigned* __restrict__ flags,            // [256] pre-zeroed
                  float* __restrict__ out)                 // [32][512][1024]
{
    __shared__ float pbuf[16 * 64 * 4];
    __shared__ float gbuf[32 * 16];
    __shared__ unsigned short xbuf[32][16];

    const int tid  = threadIdx.x;
    const int blk  = blockIdx.x;
    const int hc0  = blk * 4;
    const int wv   = tid >> 6;
    const int lane = tid & 63;

    // pack Wh slice into B-fragment order (fp16), once
    unsigned short* wb = wpk + (size_t)blk * 16384;
#pragma unroll
    for (int q = 0; q < 4; ++q) {
        int fq    = tid * 4 + q;
        int kiter = fq >> 6;
        int ln    = fq & 63;
        int col   = ln & 15;
        int g     = col >> 2, c = col & 3;
        int kbase = kiter * 32 + (ln >> 4) * 8;
        const float* Wg = (g == 0) ? Wah : ((g == 1) ? Wih : ((g == 2) ? Wfh : Woh));
        unsigned short tmp[8];
#pragma unroll
        for (int e = 0; e < 8; ++e)
            tmp[e] = __half_as_ushort(__float2half_rn(Wg[(size_t)(kbase + e) * 1024 + hc0 + c]));
        *reinterpret_cast<int4*>(wb + (size_t)fq * 8) = *reinterpret_cast<int4*>(tmp);
    }

    float biasr[4][4];
    float sreg = 0.f;
    if (tid < 128) {
        int hc = tid & 3;
        biasr[0][hc] = ba [hc0 + hc];
        biasr[1][hc] = bi [hc0 + hc];
        biasr[2][hc] = bfv[hc0 + hc];
        biasr[3][hc] = bo [hc0 + hc];
    }

    __syncthreads();

    const int koct = lane >> 4;
    const int arow = lane & 15;

    for (int t = 0; t < 512; ++t) {
        if (t > 0) {
            // S1: compiler emits s_waitcnt vmcnt(0) before s_barrier. The h
            // atomicExch ops have RETURNS pending, so vmcnt(0) == responses
            // arrived == RMWs executed at the IC. Flag is therefore published
            // strictly after h is globally visible.
            __syncthreads();
            if (tid == 0)
                __hip_atomic_store(&flags[blk], (unsigned)t, __ATOMIC_RELAXED, __HIP_MEMORY_SCOPE_AGENT);
            if (tid < 128) {                               // overlap: xg tile for step t
                int r = tid >> 2, g = tid & 3;
                ushort4 v = *reinterpret_cast<const ushort4*>(
                    xg + ((size_t)t * 32 + r) * 4096 + g * 1024 + hc0);
                *reinterpret_cast<ushort4*>(&xbuf[r][g * 4]) = v;
            }
            if (tid < 64) {
                for (;;) {
                    unsigned m0 = __hip_atomic_load(&flags[tid * 4 + 0], __ATOMIC_RELAXED, __HIP_MEMORY_SCOPE_AGENT);
                    unsigned m1 = __hip_atomic_load(&flags[tid * 4 + 1], __ATOMIC_RELAXED, __HIP_MEMORY_SCOPE_AGENT);
                    unsigned m2 = __hip_atomic_load(&flags[tid * 4 + 2], __ATOMIC_RELAXED, __HIP_MEMORY_SCOPE_AGENT);
                    unsigned m3 = __hip_atomic_load(&flags[tid * 4 + 3], __ATOMIC_RELAXED, __HIP_MEMORY_SCOPE_AGENT);
                    unsigned mn = min(min(m0, m1), min(m2, m3));
                    if (__all(mn >= (unsigned)t)) break;
                    __builtin_amdgcn_s_sleep(1);
                }
            }
            __syncthreads();
        } else {
            if (tid < 128) {
                int r = tid >> 2, g = tid & 3;
                ushort4 v = *reinterpret_cast<const ushort4*>(
                    xg + ((size_t)r * 4096) + g * 1024 + hc0);
                *reinterpret_cast<ushort4*>(&xbuf[r][g * 4]) = v;
            }
        }

        const unsigned short* hp = (t & 1) ? h16A : h16B;
        unsigned short*       hn = (t & 1) ? h16B : h16A;

        if (t > 0) {
            short8 a0[4], a1[4], b[4];
#pragma unroll
            for (int ki = 0; ki < 4; ++ki) {
                int kit = wv * 4 + ki;
                int oct = kit * 4 + koct;
                ld_sys_b128(a0[ki], hp + ((size_t)(oct * 32 + arow) * 8));
                ld_sys_b128(a1[ki], hp + ((size_t)(oct * 32 + arow + 16) * 8));
                b[ki] = *reinterpret_cast<const short8*>(wb + ((size_t)(kit * 64 + lane) * 8));
            }
            asm volatile("s_waitcnt vmcnt(0)" ::: "memory");
            __builtin_amdgcn_sched_barrier(0);

            f32x4 acc0 = {0.f, 0.f, 0.f, 0.f};
            f32x4 acc1 = {0.f, 0.f, 0.f, 0.f};
#pragma unroll
            for (int ki = 0; ki < 4; ++ki) {
                acc0 = __builtin_amdgcn_mfma_f32_16x16x32_f16(
                    __builtin_bit_cast(f16x8, a0[ki]), __builtin_bit_cast(f16x8, b[ki]), acc0, 0, 0, 0);
                acc1 = __builtin_amdgcn_mfma_f32_16x16x32_f16(
                    __builtin_bit_cast(f16x8, a1[ki]), __builtin_bit_cast(f16x8, b[ki]), acc1, 0, 0, 0);
            }
            *reinterpret_cast<f32x4*>(&pbuf[((wv * 2 + 0) * 64 + lane) * 4]) = acc0;
            *reinterpret_cast<f32x4*>(&pbuf[((wv * 2 + 1) * 64 + lane) * 4]) = acc1;
        }
        __syncthreads();

        if (t > 0) {
            int m  = tid >> 8;
            int ln = (tid >> 2) & 63;
            int rg = tid & 3;
            float s = 0.f;
#pragma unroll
            for (int w = 0; w < 8; ++w)
                s += pbuf[((w * 2 + m) * 64 + ln) * 4 + rg];
            int row = m * 16 + (ln >> 4) * 4 + rg;
            int col = ln & 15;
            gbuf[row * 16 + col] = s;
        }
        __syncthreads();

        if (tid < 128) {
            const int row = tid >> 2;
            const int hc  = tid & 3;
            float ga = (t > 0 ? gbuf[row * 16 + 0 * 4 + hc] : 0.f) + biasr[0][hc]
                     + __half2float(__ushort_as_half(xbuf[row][0 * 4 + hc]));
            float gi = (t > 0 ? gbuf[row * 16 + 1 * 4 + hc] : 0.f) + biasr[1][hc]
                     + __half2float(__ushort_as_half(xbuf[row][1 * 4 + hc]));
            float gf = (t > 0 ? gbuf[row * 16 + 2 * 4 + hc] : 0.f) + biasr[2][hc]
                     + __half2float(__ushort_as_half(xbuf[row][2 * 4 + hc]));
            float gO = (t > 0 ? gbuf[row * 16 + 3 * 4 + hc] : 0.f) + biasr[3][hc]
                     + __half2float(__ushort_as_half(xbuf[row][3 * 4 + hc]));
            float a  = tanh_f(ga);
            float ii = sigm_f(gi);
            float ff = sigm_f(gf);
            float oo = sigm_f(gO);
            sreg = a * ii + sreg * ff;
            float hv = tanh_f(sreg) * oo;

            out[((size_t)row * 512 + t) * 1024 + hc0 + hc] = hv;

            // ---- h publish via IC-side atomic WITH RETURN (the actual fix) ----
            // lanes hc, hc^1 adjacent in-wave; even lane writes the u32 word.
            int colg = hc0 + hc;
            unsigned h16v  = (unsigned)__half_as_ushort(__float2half_rn(hv));
            unsigned other = (unsigned)__shfl_xor((int)h16v, 1, 64);
            if ((hc & 1) == 0) {
                size_t u16idx = ((size_t)(colg >> 3) * 32 + row) * 8 + (colg & 7); // even
                unsigned oldv = atomicExch(reinterpret_cast<unsigned*>(hn) + (u16idx >> 1),
                                           h16v | (other << 16));
                asm volatile("" :: "v"(oldv));   // consume return: forces sc0 form,
                                                 // vmcnt now acks IC-side execution
            }
        }
    }
}

// ---------------- Fallback per-step kernel (fp32) ----------------
template<bool FIRST>
__global__ __launch_bounds__(256)
void step_kernel(const float* __restrict__ hprev, float* __restrict__ hnext,
                 float* __restrict__ sbuf, const float* __restrict__ X,
                 const float* __restrict__ Wah, const float* __restrict__ Wih,
                 const float* __restrict__ Wfh, const float* __restrict__ Woh,
                 const float* __restrict__ Wax, const float* __restrict__ Wix,
                 const float* __restrict__ Wfx, const float* __restrict__ Wox,
                 const float* __restrict__ ba, const float* __restrict__ bi,
                 const float* __restrict__ bfv, const float* __restrict__ bo,
                 float* __restrict__ out, int t)
{
    __shared__ float hs[32 * 1028];
    __shared__ float gs[2][32][16];

    const int tid  = threadIdx.x;
    const int hc0  = blockIdx.x * 4;
    const int kh   = tid >> 7;
    const int gtid = tid & 127;
    const int r    = gtid >> 2;
    const int gate = gtid & 3;
    const int k0   = kh * 512;

    float4 acc = make_float4(0.f, 0.f, 0.f, 0.f);

    if (!FIRST) {
        for (int u = 0; u < 32; u++) {
            int f4 = u * 256 + tid;
            int rr = f4 >> 8;
            int kq = (f4 & 255) << 2;
            *reinterpret_cast<float4*>(&hs[rr * 1028 + kq]) =
                *reinterpret_cast<const float4*>(hprev + rr * 1024 + kq);
        }
        __syncthreads();
        const float* Wg = (gate == 0) ? Wah : ((gate == 1) ? Wih : ((gate == 2) ? Wfh : Woh));
        const float* Wp = Wg + hc0;
#pragma unroll 4
        for (int k = k0; k < k0 + 512; k += 4) {
            float4 hv = *reinterpret_cast<const float4*>(&hs[r * 1028 + k]);
            float4 w0 = *reinterpret_cast<const float4*>(Wp + (size_t)(k + 0) * 1024);
            float4 w1 = *reinterpret_cast<const float4*>(Wp + (size_t)(k + 1) * 1024);
            float4 w2 = *reinterpret_cast<const float4*>(Wp + (size_t)(k + 2) * 1024);
            float4 w3 = *reinterpret_cast<const float4*>(Wp + (size_t)(k + 3) * 1024);
            acc.x += hv.x * w0.x + hv.y * w1.x + hv.z * w2.x + hv.w * w3.x;
            acc.y += hv.x * w0.y + hv.y * w1.y + hv.z * w2.y + hv.w * w3.y;
            acc.z += hv.x * w0.z + hv.y * w1.z + hv.z * w2.z + hv.w * w3.z;
            acc.w += hv.x * w0.w + hv.y * w1.w + hv.z * w2.w + hv.w * w3.w;
        }
    }
    {
        __syncthreads();
        for (int u = 0; u < 32; u++) {
            int f4 = u * 256 + tid;
            int rr = f4 >> 8;
            int kq = (f4 & 255) << 2;
            *reinterpret_cast<float4*>(&hs[rr * 1028 + kq]) =
                *reinterpret_cast<const float4*>(X + ((size_t)rr * 512 + t) * 1024 + kq);
        }
        __syncthreads();
        const float* Wg = (gate == 0) ? Wax : ((gate == 1) ? Wix : ((gate == 2) ? Wfx : Wox));
        const float* Wp = Wg + hc0;
#pragma unroll 4
        for (int k = k0; k < k0 + 512; k += 4) {
            float4 hv = *reinterpret_cast<const float4*>(&hs[r * 1028 + k]);
            float4 w0 = *reinterpret_cast<const float4*>(Wp + (size_t)(k + 0) * 1024);
            float4 w1 = *reinterpret_cast<const float4*>(Wp + (size_t)(k + 1) * 1024);
            float4 w2 = *reinterpret_cast<const float4*>(Wp + (size_t)(k + 2) * 1024);
            float4 w3 = *reinterpret_cast<const float4*>(Wp + (size_t)(k + 3) * 1024);
            acc.x += hv.x * w0.x + hv.y * w1.x + hv.z * w2.x + hv.w * w3.x;
            acc.y += hv.x * w0.y + hv.y * w1.y + hv.z * w2.y + hv.w * w3.y;
            acc.z += hv.x * w0.z + hv.y * w1.z + hv.z * w2.z + hv.w * w3.z;
            acc.w += hv.x * w0.w + hv.y * w1.w + hv.z * w2.w + hv.w * w3.w;
        }
    }

    *reinterpret_cast<float4*>(&gs[kh][r][gate * 4]) = acc;
    __syncthreads();

    if (tid < 128) {
        const int rr = tid >> 2;
        const int hcl = tid & 3;
        const int h  = hc0 + hcl;
        float ga = gs[0][rr][0 + hcl]  + gs[1][rr][0 + hcl]  + ba[h];
        float gi = gs[0][rr][4 + hcl]  + gs[1][rr][4 + hcl]  + bi[h];
        float gf = gs[0][rr][8 + hcl]  + gs[1][rr][8 + hcl]  + bfv[h];
        float gO = gs[0][rr][12 + hcl] + gs[1][rr][12 + hcl] + bo[h];
        float a = tanh_f(ga);
        float i = sigm_f(gi);
        float f = sigm_f(gf);
        float o = sigm_f(gO);
        float sprev = FIRST ? 0.f : sbuf[rr * 1024 + h];
        float s = a * i + sprev * f;
        sbuf[rr * 1024 + h] = s;
        float hv = tanh_f(s) * o;
        hnext[rr * 1024 + h] = hv;
        out[((size_t)rr * 512 + t) * 1024 + h] = hv;
    }
}

extern "C" void kernel_launch(void* const* d_in, const int* in_sizes, int n_in,
                              void* d_out, int out_size, void* d_ws, size_t ws_size,
                              hipStream_t stream)
{
    const float* X   = (const float*)d_in[0];
    const float* Wax = (const float*)d_in[1];
    const float* Wix = (const float*)d_in[2];
    const float* Wfx = (const float*)d_in[3];
    const float* Wox = (const float*)d_in[4];
    const float* Wah = (const float*)d_in[5];
    const float* Wih = (const float*)d_in[6];
    const float* Wfh = (const float*)d_in[7];
    const float* Woh = (const float*)d_in[8];
    const float* ba  = (const float*)d_in[9];
    const float* bi  = (const float*)d_in[10];
    const float* bfv = (const float*)d_in[11];
    const float* bo  = (const float*)d_in[12];
    float* out = (float*)d_out;

    const size_t XGH  = (size_t)512 * 32 * 4096 * 2;      // 128 MiB fp16 xg
    const size_t WPK  = (size_t)256 * 16384 * 2;          // 8 MiB fp16 packed Wh
    const size_t WTX  = (size_t)4096 * 1024 * 2;          // 8 MiB fp16 Wt
    const size_t H16  = (size_t)32 * 1024 * 2;            // 64 KiB fp16 h
    const size_t BAR  = 4096;
    const size_t HBF  = (size_t)32 * 1024 * 4;

    char* ws = (char*)d_ws;
    const bool big = ws_size >= XGH + WPK + WTX + 2 * H16 + BAR;

    if (big) {
        unsigned short* xg    = (unsigned short*)ws;
        unsigned short* wpk   = (unsigned short*)(ws + XGH);
        unsigned short* Wt    = (unsigned short*)(ws + XGH + WPK);
        unsigned short* h16A  = (unsigned short*)(ws + XGH + WPK + WTX);
        unsigned short* h16B  = (unsigned short*)(ws + XGH + WPK + WTX + H16);
        unsigned*       flags = (unsigned*)(ws + XGH + WPK + WTX + 2 * H16);

        hipMemsetAsync(flags, 0, BAR, stream);
        wtrans_kernel<<<1024, 256, 0, stream>>>(Wax, Wix, Wfx, Wox, Wt);
        proj_mfma<<<4096, 256, 0, stream>>>(X, (const _Float16*)Wt, xg);

        const unsigned short* xgu = xg;
        void* args[] = {
            (void*)&xgu,
            (void*)&Wah, (void*)&Wih, (void*)&Wfh, (void*)&Woh,
            (void*)&ba, (void*)&bi, (void*)&bfv, (void*)&bo,
            (void*)&wpk, (void*)&h16A, (void*)&h16B,
            (void*)&flags, (void*)&out
        };
        hipLaunchCooperativeKernel((void*)lstm_persist, dim3(256), dim3(512),
                                   args, 0, stream);
    } else {
        float* h0 = (float*)ws;
        float* h1 = (float*)(ws + HBF);
        float* sb = (float*)(ws + 2 * HBF);
        float* hb[2] = { h0, h1 };
        for (int t = 0; t < 512; ++t) {
            const float* hprev = hb[(t + 1) & 1];
            float* hnext = hb[t & 1];
            if (t == 0)
                step_kernel<true><<<256, 256, 0, stream>>>(hprev, hnext, sb, X,
                    Wah, Wih, Wfh, Woh, Wax, Wix, Wfx, Wox, ba, bi, bfv, bo, out, t);
            else
                step_kernel<false><<<256, 256, 0, stream>>>(hprev, hnext, sb, X,
                    Wah, Wih, Wfh, Woh, Wax, Wix, Wfx, Wox, ba, bi, bfv, bo, out, t);
        }
    }
}

// Round 12
// 2122.944 us; speedup vs baseline: 2.0634x; 1.0658x over previous
//
#include <hip/hip_runtime.h>
#include <hip/hip_fp16.h>

// LSTM: B=32, T=512, D=1024, H=1024.
// Round-11 validated base (correct returning-atomic h publish) + two micro
// trims validated inside round-6's kernel: (1) fused reduce+gates (gate
// threads gather wave partials directly from pbuf; drops gbuf + one sync),
// (2) W-fragment loads hoisted above the S1 barrier (L1 hits, latency moved
// off the post-barrier critical path).

typedef __attribute__((ext_vector_type(8))) _Float16 f16x8;
typedef __attribute__((ext_vector_type(8))) short    short8;
typedef __attribute__((ext_vector_type(4))) float    f32x4;

__device__ __forceinline__ float sigm_f(float x) { return 1.0f / (1.0f + __expf(-x)); }
__device__ __forceinline__ float tanh_f(float x) { return 1.0f - 2.0f / (__expf(2.0f * x) + 1.0f); }

__device__ __forceinline__ void ld_sys_b128(short8& d, const void* p) {
    asm volatile("global_load_dwordx4 %0, %1, off sc0 sc1" : "=v"(d) : "v"(p) : "memory");
}

// ---------------- W transpose + fp16 convert ----------------
__global__ __launch_bounds__(256)
void wtrans_kernel(const float* __restrict__ Wa, const float* __restrict__ Wi,
                   const float* __restrict__ Wf, const float* __restrict__ Wo,
                   unsigned short* __restrict__ Wt)
{
    __shared__ float Ts[64][65];
    const int bx = blockIdx.x;
    const int g  = bx >> 8;
    const int k0 = ((bx >> 4) & 15) * 64;
    const int c0 = (bx & 15) * 64;
    const float* W = (g == 0) ? Wa : ((g == 1) ? Wi : ((g == 2) ? Wf : Wo));
    const int tid = threadIdx.x;
#pragma unroll
    for (int u = 0; u < 4; ++u) {
        int r  = u * 16 + (tid >> 4);
        int c4 = (tid & 15) * 4;
        float4 v = *reinterpret_cast<const float4*>(W + (size_t)(k0 + r) * 1024 + c0 + c4);
        Ts[r][c4 + 0] = v.x; Ts[r][c4 + 1] = v.y; Ts[r][c4 + 2] = v.z; Ts[r][c4 + 3] = v.w;
    }
    __syncthreads();
#pragma unroll
    for (int u = 0; u < 4; ++u) {
        int col = u * 16 + (tid >> 4);
        int k4  = (tid & 15) * 4;
        unsigned short o[4];
#pragma unroll
        for (int j = 0; j < 4; ++j)
            o[j] = __half_as_ushort(__float2half_rn(Ts[k4 + j][col]));
        *reinterpret_cast<ushort4*>(Wt + ((size_t)g * 1024 + c0 + col) * 1024 + k0 + k4) =
            *reinterpret_cast<ushort4*>(o);
    }
}

// ---------------- Projection GEMM via fp16 MFMA ----------------
__global__ __launch_bounds__(256)
void proj_mfma(const float* __restrict__ X,
               const _Float16* __restrict__ Wt,
               unsigned short* __restrict__ xg)
{
    __shared__ _Float16 As[128 * 40];
    __shared__ _Float16 Bs[128 * 40];

    const int tid  = threadIdx.x;
    const int bn   = blockIdx.x & 31;
    const int bm   = blockIdx.x >> 5;
    const int row0 = bm * 128, col0 = bn * 128;
    const int w    = tid >> 6, lane = tid & 63;
    const int wm   = w >> 1,  wn   = w & 1;
    const int lr   = lane & 15, ko = lane >> 4;

    f32x4 acc[4][4];
#pragma unroll
    for (int mi = 0; mi < 4; ++mi)
#pragma unroll
        for (int ni = 0; ni < 4; ++ni)
            acc[mi][ni] = f32x4{0.f, 0.f, 0.f, 0.f};

    for (int kt = 0; kt < 1024; kt += 32) {
#pragma unroll
        for (int u = 0; u < 4; ++u) {
            int f4 = u * 256 + tid;
            int r  = f4 >> 3, kq = (f4 & 7) * 4;
            float4 v = *reinterpret_cast<const float4*>(X + (size_t)(row0 + r) * 1024 + kt + kq);
            _Float16 h4[4] = {(_Float16)v.x, (_Float16)v.y, (_Float16)v.z, (_Float16)v.w};
            *reinterpret_cast<double*>(&As[r * 40 + kq]) = *reinterpret_cast<double*>(h4);
        }
#pragma unroll
        for (int u = 0; u < 2; ++u) {
            int i8  = u * 256 + tid;
            int col = i8 >> 2, k8 = (i8 & 3) * 8;
            *reinterpret_cast<float4*>(&Bs[col * 40 + k8]) =
                *reinterpret_cast<const float4*>(Wt + (size_t)(col0 + col) * 1024 + kt + k8);
        }
        __syncthreads();

        f16x8 af[4], bf[4];
#pragma unroll
        for (int mi = 0; mi < 4; ++mi)
            af[mi] = *reinterpret_cast<const f16x8*>(&As[(wm * 64 + mi * 16 + lr) * 40 + ko * 8]);
#pragma unroll
        for (int ni = 0; ni < 4; ++ni)
            bf[ni] = *reinterpret_cast<const f16x8*>(&Bs[(wn * 64 + ni * 16 + lr) * 40 + ko * 8]);
#pragma unroll
        for (int mi = 0; mi < 4; ++mi)
#pragma unroll
            for (int ni = 0; ni < 4; ++ni)
                acc[mi][ni] = __builtin_amdgcn_mfma_f32_16x16x32_f16(af[mi], bf[ni], acc[mi][ni], 0, 0, 0);
        __syncthreads();
    }

#pragma unroll
    for (int mi = 0; mi < 4; ++mi)
#pragma unroll
        for (int ni = 0; ni < 4; ++ni)
#pragma unroll
            for (int j = 0; j < 4; ++j) {
                int rt = row0 + wm * 64 + mi * 16 + ko * 4 + j;
                int ct = col0 + wn * 64 + ni * 16 + lr;
                int b = rt >> 9, t = rt & 511;
                xg[((size_t)t * 32 + b) * 4096 + ct] =
                    __half_as_ushort(__float2half_rn(acc[mi][ni][j]));
            }
}

// ---------------- Persistent MFMA recurrent kernel ----------------
// 256 blocks x 512 threads (cooperative). Block owns h-cols [blk*4,+4) = 16 gate-cols.
// Per step: [hoisted b loads] -> S1 (drain h atomics WITH returns == h at IC)
// -> flag publish + xg stage + 64-lane poll -> S2 -> a sc-loads + MFMA ->
// pbuf -> S3 -> fused gather+gates + h publish (returning atomicExch) + out.
__global__ __launch_bounds__(512)
void lstm_persist(const unsigned short* __restrict__ xg,   // [512][32][4096] fp16
                  const float* __restrict__ Wah, const float* __restrict__ Wih,
                  const float* __restrict__ Wfh, const float* __restrict__ Woh,
                  const float* __restrict__ ba, const float* __restrict__ bi,
                  const float* __restrict__ bfv, const float* __restrict__ bo,
                  unsigned short* __restrict__ wpk,        // [256][16384] fp16 B-frag order
                  unsigned short* __restrict__ h16A,       // [128][32][8] fp16
                  unsigned short* __restrict__ h16B,
                  unsigned* __restrict__ flags,            // [256] pre-zeroed
                  float* __restrict__ out)                 // [32][512][1024]
{
    __shared__ float pbuf[16 * 64 * 4];
    __shared__ unsigned short xbuf[32][16];

    const int tid  = threadIdx.x;
    const int blk  = blockIdx.x;
    const int hc0  = blk * 4;
    const int wv   = tid >> 6;
    const int lane = tid & 63;

    // pack Wh slice into B-fragment order (fp16), once
    unsigned short* wb = wpk + (size_t)blk * 16384;
#pragma unroll
    for (int q = 0; q < 4; ++q) {
        int fq    = tid * 4 + q;
        int kiter = fq >> 6;
        int ln    = fq & 63;
        int col   = ln & 15;
        int g     = col >> 2, c = col & 3;
        int kbase = kiter * 32 + (ln >> 4) * 8;
        const float* Wg = (g == 0) ? Wah : ((g == 1) ? Wih : ((g == 2) ? Wfh : Woh));
        unsigned short tmp[8];
#pragma unroll
        for (int e = 0; e < 8; ++e)
            tmp[e] = __half_as_ushort(__float2half_rn(Wg[(size_t)(kbase + e) * 1024 + hc0 + c]));
        *reinterpret_cast<int4*>(wb + (size_t)fq * 8) = *reinterpret_cast<int4*>(tmp);
    }

    float biasr[4][4];
    float sreg = 0.f;
    if (tid < 128) {
        int hc = tid & 3;
        biasr[0][hc] = ba [hc0 + hc];
        biasr[1][hc] = bi [hc0 + hc];
        biasr[2][hc] = bfv[hc0 + hc];
        biasr[3][hc] = bo [hc0 + hc];
    }

    __syncthreads();

    const int koct = lane >> 4;
    const int arow = lane & 15;

    for (int t = 0; t < 512; ++t) {
        // hoisted W-frag loads (h-independent, L1-hot; latency spans the barrier)
        short8 b[4];
        if (t > 0) {
#pragma unroll
            for (int ki = 0; ki < 4; ++ki)
                b[ki] = *reinterpret_cast<const short8*>(wb + ((size_t)((wv * 4 + ki) * 64 + lane) * 8));
        }

        if (t > 0) {
            // S1: pre-barrier vmcnt(0) drains the RETURNING h atomics (ack ==
            // executed at IC) -> flag below is published strictly after h visible.
            __syncthreads();
            if (tid == 0)
                __hip_atomic_store(&flags[blk], (unsigned)t, __ATOMIC_RELAXED, __HIP_MEMORY_SCOPE_AGENT);
            if (tid < 128) {                               // overlap: xg tile for step t
                int r = tid >> 2, g = tid & 3;
                ushort4 v = *reinterpret_cast<const ushort4*>(
                    xg + ((size_t)t * 32 + r) * 4096 + g * 1024 + hc0);
                *reinterpret_cast<ushort4*>(&xbuf[r][g * 4]) = v;
            }
            if (tid < 64) {
                for (;;) {
                    unsigned m0 = __hip_atomic_load(&flags[tid * 4 + 0], __ATOMIC_RELAXED, __HIP_MEMORY_SCOPE_AGENT);
                    unsigned m1 = __hip_atomic_load(&flags[tid * 4 + 1], __ATOMIC_RELAXED, __HIP_MEMORY_SCOPE_AGENT);
                    unsigned m2 = __hip_atomic_load(&flags[tid * 4 + 2], __ATOMIC_RELAXED, __HIP_MEMORY_SCOPE_AGENT);
                    unsigned m3 = __hip_atomic_load(&flags[tid * 4 + 3], __ATOMIC_RELAXED, __HIP_MEMORY_SCOPE_AGENT);
                    unsigned mn = min(min(m0, m1), min(m2, m3));
                    if (__all(mn >= (unsigned)t)) break;
                    __builtin_amdgcn_s_sleep(1);
                }
            }
            __syncthreads();                               // S2
        } else {
            if (tid < 128) {
                int r = tid >> 2, g = tid & 3;
                ushort4 v = *reinterpret_cast<const ushort4*>(
                    xg + ((size_t)r * 4096) + g * 1024 + hc0);
                *reinterpret_cast<ushort4*>(&xbuf[r][g * 4]) = v;
            }
        }

        const unsigned short* hp = (t & 1) ? h16A : h16B;
        unsigned short*       hn = (t & 1) ? h16B : h16A;

        if (t > 0) {
            short8 a0[4], a1[4];
#pragma unroll
            for (int ki = 0; ki < 4; ++ki) {
                int kit = wv * 4 + ki;
                int oct = kit * 4 + koct;
                ld_sys_b128(a0[ki], hp + ((size_t)(oct * 32 + arow) * 8));
                ld_sys_b128(a1[ki], hp + ((size_t)(oct * 32 + arow + 16) * 8));
            }
            asm volatile("s_waitcnt vmcnt(0)" ::: "memory");
            __builtin_amdgcn_sched_barrier(0);

            f32x4 acc0 = {0.f, 0.f, 0.f, 0.f};
            f32x4 acc1 = {0.f, 0.f, 0.f, 0.f};
#pragma unroll
            for (int ki = 0; ki < 4; ++ki) {
                acc0 = __builtin_amdgcn_mfma_f32_16x16x32_f16(
                    __builtin_bit_cast(f16x8, a0[ki]), __builtin_bit_cast(f16x8, b[ki]), acc0, 0, 0, 0);
                acc1 = __builtin_amdgcn_mfma_f32_16x16x32_f16(
                    __builtin_bit_cast(f16x8, a1[ki]), __builtin_bit_cast(f16x8, b[ki]), acc1, 0, 0, 0);
            }
            *reinterpret_cast<f32x4*>(&pbuf[((wv * 2 + 0) * 64 + lane) * 4]) = acc0;
            *reinterpret_cast<f32x4*>(&pbuf[((wv * 2 + 1) * 64 + lane) * 4]) = acc1;
        }
        __syncthreads();                                   // S3: partials visible

        if (tid < 128) {
            // fused 8-way gather + gates (mapping validated rounds 6/7)
            const int row = tid >> 2;
            const int hc  = tid & 3;
            const int m   = row >> 4;
            const int rp  = row & 15;
            const int rg  = rp & 3;
            const int lh  = (rp >> 2) * 16;
            float gsum[4] = {0.f, 0.f, 0.f, 0.f};
            if (t > 0) {
#pragma unroll
                for (int g = 0; g < 4; ++g) {
                    int ln = lh + g * 4 + hc;
                    float s = 0.f;
#pragma unroll
                    for (int w = 0; w < 8; ++w)
                        s += pbuf[((w * 2 + m) * 64 + ln) * 4 + rg];
                    gsum[g] = s;
                }
            }
            float ga = gsum[0] + biasr[0][hc] + __half2float(__ushort_as_half(xbuf[row][0 * 4 + hc]));
            float gi = gsum[1] + biasr[1][hc] + __half2float(__ushort_as_half(xbuf[row][1 * 4 + hc]));
            float gf = gsum[2] + biasr[2][hc] + __half2float(__ushort_as_half(xbuf[row][2 * 4 + hc]));
            float gO = gsum[3] + biasr[3][hc] + __half2float(__ushort_as_half(xbuf[row][3 * 4 + hc]));
            float a  = tanh_f(ga);
            float ii = sigm_f(gi);
            float ff = sigm_f(gf);
            float oo = sigm_f(gO);
            sreg = a * ii + sreg * ff;
            float hv = tanh_f(sreg) * oo;

            out[((size_t)row * 512 + t) * 1024 + hc0 + hc] = hv;

            // h publish via IC-side atomic WITH RETURN (validated round 11)
            int colg = hc0 + hc;
            unsigned h16v  = (unsigned)__half_as_ushort(__float2half_rn(hv));
            unsigned other = (unsigned)__shfl_xor((int)h16v, 1, 64);
            if ((hc & 1) == 0) {
                size_t u16idx = ((size_t)(colg >> 3) * 32 + row) * 8 + (colg & 7); // even
                unsigned oldv = atomicExch(reinterpret_cast<unsigned*>(hn) + (u16idx >> 1),
                                           h16v | (other << 16));
                asm volatile("" :: "v"(oldv));   // consume return: ack == at-IC
            }
        }
    }
}

// ---------------- Fallback per-step kernel (fp32) ----------------
template<bool FIRST>
__global__ __launch_bounds__(256)
void step_kernel(const float* __restrict__ hprev, float* __restrict__ hnext,
                 float* __restrict__ sbuf, const float* __restrict__ X,
                 const float* __restrict__ Wah, const float* __restrict__ Wih,
                 const float* __restrict__ Wfh, const float* __restrict__ Woh,
                 const float* __restrict__ Wax, const float* __restrict__ Wix,
                 const float* __restrict__ Wfx, const float* __restrict__ Wox,
                 const float* __restrict__ ba, const float* __restrict__ bi,
                 const float* __restrict__ bfv, const float* __restrict__ bo,
                 float* __restrict__ out, int t)
{
    __shared__ float hs[32 * 1028];
    __shared__ float gs[2][32][16];

    const int tid  = threadIdx.x;
    const int hc0  = blockIdx.x * 4;
    const int kh   = tid >> 7;
    const int gtid = tid & 127;
    const int r    = gtid >> 2;
    const int gate = gtid & 3;
    const int k0   = kh * 512;

    float4 acc = make_float4(0.f, 0.f, 0.f, 0.f);

    if (!FIRST) {
        for (int u = 0; u < 32; u++) {
            int f4 = u * 256 + tid;
            int rr = f4 >> 8;
            int kq = (f4 & 255) << 2;
            *reinterpret_cast<float4*>(&hs[rr * 1028 + kq]) =
                *reinterpret_cast<const float4*>(hprev + rr * 1024 + kq);
        }
        __syncthreads();
        const float* Wg = (gate == 0) ? Wah : ((gate == 1) ? Wih : ((gate == 2) ? Wfh : Woh));
        const float* Wp = Wg + hc0;
#pragma unroll 4
        for (int k = k0; k < k0 + 512; k += 4) {
            float4 hv = *reinterpret_cast<const float4*>(&hs[r * 1028 + k]);
            float4 w0 = *reinterpret_cast<const float4*>(Wp + (size_t)(k + 0) * 1024);
            float4 w1 = *reinterpret_cast<const float4*>(Wp + (size_t)(k + 1) * 1024);
            float4 w2 = *reinterpret_cast<const float4*>(Wp + (size_t)(k + 2) * 1024);
            float4 w3 = *reinterpret_cast<const float4*>(Wp + (size_t)(k + 3) * 1024);
            acc.x += hv.x * w0.x + hv.y * w1.x + hv.z * w2.x + hv.w * w3.x;
            acc.y += hv.x * w0.y + hv.y * w1.y + hv.z * w2.y + hv.w * w3.y;
            acc.z += hv.x * w0.z + hv.y * w1.z + hv.z * w2.z + hv.w * w3.z;
            acc.w += hv.x * w0.w + hv.y * w1.w + hv.z * w2.w + hv.w * w3.w;
        }
    }
    {
        __syncthreads();
        for (int u = 0; u < 32; u++) {
            int f4 = u * 256 + tid;
            int rr = f4 >> 8;
            int kq = (f4 & 255) << 2;
            *reinterpret_cast<float4*>(&hs[rr * 1028 + kq]) =
                *reinterpret_cast<const float4*>(X + ((size_t)rr * 512 + t) * 1024 + kq);
        }
        __syncthreads();
        const float* Wg = (gate == 0) ? Wax : ((gate == 1) ? Wix : ((gate == 2) ? Wfx : Wox));
        const float* Wp = Wg + hc0;
#pragma unroll 4
        for (int k = k0; k < k0 + 512; k += 4) {
            float4 hv = *reinterpret_cast<const float4*>(&hs[r * 1028 + k]);
            float4 w0 = *reinterpret_cast<const float4*>(Wp + (size_t)(k + 0) * 1024);
            float4 w1 = *reinterpret_cast<const float4*>(Wp + (size_t)(k + 1) * 1024);
            float4 w2 = *reinterpret_cast<const float4*>(Wp + (size_t)(k + 2) * 1024);
            float4 w3 = *reinterpret_cast<const float4*>(Wp + (size_t)(k + 3) * 1024);
            acc.x += hv.x * w0.x + hv.y * w1.x + hv.z * w2.x + hv.w * w3.x;
            acc.y += hv.x * w0.y + hv.y * w1.y + hv.z * w2.y + hv.w * w3.y;
            acc.z += hv.x * w0.z + hv.y * w1.z + hv.z * w2.z + hv.w * w3.z;
            acc.w += hv.x * w0.w + hv.y * w1.w + hv.z * w2.w + hv.w * w3.w;
        }
    }

    *reinterpret_cast<float4*>(&gs[kh][r][gate * 4]) = acc;
    __syncthreads();

    if (tid < 128) {
        const int rr = tid >> 2;
        const int hcl = tid & 3;
        const int h  = hc0 + hcl;
        float ga = gs[0][rr][0 + hcl]  + gs[1][rr][0 + hcl]  + ba[h];
        float gi = gs[0][rr][4 + hcl]  + gs[1][rr][4 + hcl]  + bi[h];
        float gf = gs[0][rr][8 + hcl]  + gs[1][rr][8 + hcl]  + bfv[h];
        float gO = gs[0][rr][12 + hcl] + gs[1][rr][12 + hcl] + bo[h];
        float a = tanh_f(ga);
        float i = sigm_f(gi);
        float f = sigm_f(gf);
        float o = sigm_f(gO);
        float sprev = FIRST ? 0.f : sbuf[rr * 1024 + h];
        float s = a * i + sprev * f;
        sbuf[rr * 1024 + h] = s;
        float hv = tanh_f(s) * o;
        hnext[rr * 1024 + h] = hv;
        out[((size_t)rr * 512 + t) * 1024 + h] = hv;
    }
}

extern "C" void kernel_launch(void* const* d_in, const int* in_sizes, int n_in,
                              void* d_out, int out_size, void* d_ws, size_t ws_size,
                              hipStream_t stream)
{
    const float* X   = (const float*)d_in[0];
    const float* Wax = (const float*)d_in[1];
    const float* Wix = (const float*)d_in[2];
    const float* Wfx = (const float*)d_in[3];
    const float* Wox = (const float*)d_in[4];
    const float* Wah = (const float*)d_in[5];
    const float* Wih = (const float*)d_in[6];
    const float* Wfh = (const float*)d_in[7];
    const float* Woh = (const float*)d_in[8];
    const float* ba  = (const float*)d_in[9];
    const float* bi  = (const float*)d_in[10];
    const float* bfv = (const float*)d_in[11];
    const float* bo  = (const float*)d_in[12];
    float* out = (float*)d_out;

    const size_t XGH  = (size_t)512 * 32 * 4096 * 2;      // 128 MiB fp16 xg
    const size_t WPK  = (size_t)256 * 16384 * 2;          // 8 MiB fp16 packed Wh
    const size_t WTX  = (size_t)4096 * 1024 * 2;          // 8 MiB fp16 Wt
    const size_t H16  = (size_t)32 * 1024 * 2;            // 64 KiB fp16 h
    const size_t BAR  = 4096;
    const size_t HBF  = (size_t)32 * 1024 * 4;

    char* ws = (char*)d_ws;
    const bool big = ws_size >= XGH + WPK + WTX + 2 * H16 + BAR;

    if (big) {
        unsigned short* xg    = (unsigned short*)ws;
        unsigned short* wpk   = (unsigned short*)(ws + XGH);
        unsigned short* Wt    = (unsigned short*)(ws + XGH + WPK);
        unsigned short* h16A  = (unsigned short*)(ws + XGH + WPK + WTX);
        unsigned short* h16B  = (unsigned short*)(ws + XGH + WPK + WTX + H16);
        unsigned*       flags = (unsigned*)(ws + XGH + WPK + WTX + 2 * H16);

        hipMemsetAsync(flags, 0, BAR, stream);
        wtrans_kernel<<<1024, 256, 0, stream>>>(Wax, Wix, Wfx, Wox, Wt);
        proj_mfma<<<4096, 256, 0, stream>>>(X, (const _Float16*)Wt, xg);

        const unsigned short* xgu = xg;
        void* args[] = {
            (void*)&xgu,
            (void*)&Wah, (void*)&Wih, (void*)&Wfh, (void*)&Woh,
            (void*)&ba, (void*)&bi, (void*)&bfv, (void*)&bo,
            (void*)&wpk, (void*)&h16A, (void*)&h16B,
            (void*)&flags, (void*)&out
        };
        hipLaunchCooperativeKernel((void*)lstm_persist, dim3(256), dim3(512),
                                   args, 0, stream);
    } else {
        float* h0 = (float*)ws;
        float* h1 = (float*)(ws + HBF);
        float* sb = (float*)(ws + 2 * HBF);
        float* hb[2] = { h0, h1 };
        for (int t = 0; t < 512; ++t) {
            const float* hprev = hb[(t + 1) & 1];
            float* hnext = hb[t & 1];
            if (t == 0)
                step_kernel<true><<<256, 256, 0, stream>>>(hprev, hnext, sb, X,
                    Wah, Wih, Wfh, Woh, Wax, Wix, Wfx, Wox, ba, bi, bfv, bo, out, t);
            else
                step_kernel<false><<<256, 256, 0, stream>>>(hprev, hnext, sb, X,
                    Wah, Wih, Wfh, Woh, Wax, Wix, Wfx, Wox, ba, bi, bfv, bo, out, t);
        }
    }
}